// Round 10
// baseline (1328.762 us; speedup 1.0000x reference)
//
#include <hip/hip_runtime.h>
#include <hip/hip_bf16.h>
#include <hip/hip_fp16.h>
#include <math.h>

// Problem constants
constexpr int cB   = 2;
constexpr int cS   = 2048;
constexpr int cD   = 1024;
constexpr int cQH  = 16;
constexpr int cKVH = 4;
constexpr int cDH  = 64;
constexpr int cTOPK = 128;
constexpr int cM   = cB * cS;          // 4096 rows for all GEMMs
constexpr int cNB  = cS / 64;          // 32 j-blocks of 64
constexpr int cLSZ = 384;              // kept-list capacity (128 + tie slack)

typedef __attribute__((ext_vector_type(8))) short short8;
typedef __attribute__((ext_vector_type(4))) float floatx4;
typedef _Float16 half2_t __attribute__((ext_vector_type(2)));

#if defined(__has_builtin)
#if __has_builtin(__builtin_amdgcn_fdot2)
#define HAS_FDOT2 1
#endif
#endif

// fp32 -> bf16 round-to-nearest-even (no NaN inputs in this problem)
__device__ inline ushort f2bf(float f) {
    unsigned u = __float_as_uint(f);
    return (ushort)((u + 0x7FFFu + ((u >> 16) & 1u)) >> 16);
}

// f16 pair dot with fp32 accumulate: v_dot2_f32_f16 (1 inst per 2 values)
__device__ inline float fdot2f(unsigned k, unsigned q, float c) {
#ifdef HAS_FDOT2
    return __builtin_amdgcn_fdot2(__builtin_bit_cast(half2_t, k),
                                  __builtin_bit_cast(half2_t, q), c, false);
#else
    __half2 kk = __builtin_bit_cast(__half2, k);
    __half2 qq = __builtin_bit_cast(__half2, q);
    float2 kf2 = __half22float2(kk), qf2 = __half22float2(qq);
    return c + kf2.x * qf2.x + kf2.y * qf2.y;
#endif
}

// ---------------------------------------------------------------------------
// Cast fp32 -> bf16 (raw ushort), n multiple of 4.
// ---------------------------------------------------------------------------
__global__ void cast_f32_bf16(const float* __restrict__ src,
                              ushort* __restrict__ dst, int n) {
    int i4 = (blockIdx.x * blockDim.x + threadIdx.x) * 4;
    if (i4 >= n) return;
    const float4 v = *(const float4*)(src + i4);
    ushort4 r;
    r.x = f2bf(v.x); r.y = f2bf(v.y); r.z = f2bf(v.z); r.w = f2bf(v.w);
    *(ushort4*)(dst + i4) = r;
}

// ---------------------------------------------------------------------------
// MFMA bf16 GEMM: C[m][n] = sum_k A[m][k] * W[n][k]  (A @ W^T).
// 128x128 block tile, BK=32, 256 threads = 4 waves (2x2 of 64x64).
// ---------------------------------------------------------------------------
__global__ __launch_bounds__(256) void gemm_bf16_bt(
        const ushort* __restrict__ A, const ushort* __restrict__ W,
        float* __restrict__ C, int M, int N, int K) {
    __shared__ short As[4][128][8];
    __shared__ short Bs[4][128][8];

    const int tid  = threadIdx.x;
    const int lane = tid & 63;
    const int w    = tid >> 6;          // 0..3
    const int wm   = (w & 1) * 64;
    const int wn   = (w >> 1) * 64;
    const int m0   = blockIdx.y * 128;
    const int n0   = blockIdx.x * 128;

    const int quad = lane >> 4;
    const int l16  = lane & 15;

    floatx4 acc[4][4];
    #pragma unroll
    for (int mi = 0; mi < 4; ++mi)
        #pragma unroll
        for (int ni = 0; ni < 4; ++ni)
            acc[mi][ni] = (floatx4){0.f, 0.f, 0.f, 0.f};

    const int sr = tid >> 1;            // staging row 0..127
    const int sh = (tid & 1) * 2;       // k-chunk pair 0 or 2

    for (int k0 = 0; k0 < K; k0 += 32) {
        const ushort* sa = A + (size_t)(m0 + sr) * K + k0 + sh * 8;
        const short8 a0 = *(const short8*)sa;
        const short8 a1 = *(const short8*)(sa + 8);
        const ushort* sw = W + (size_t)(n0 + sr) * K + k0 + sh * 8;
        const short8 b0 = *(const short8*)sw;
        const short8 b1 = *(const short8*)(sw + 8);
        *(short8*)&As[sh][sr][0]     = a0;
        *(short8*)&As[sh + 1][sr][0] = a1;
        *(short8*)&Bs[sh][sr][0]     = b0;
        *(short8*)&Bs[sh + 1][sr][0] = b1;
        __syncthreads();

        short8 af[4], bf[4];
        #pragma unroll
        for (int mi = 0; mi < 4; ++mi)
            af[mi] = *(const short8*)&As[quad][wm + mi * 16 + l16][0];
        #pragma unroll
        for (int ni = 0; ni < 4; ++ni)
            bf[ni] = *(const short8*)&Bs[quad][wn + ni * 16 + l16][0];
        #pragma unroll
        for (int mi = 0; mi < 4; ++mi)
            #pragma unroll
            for (int ni = 0; ni < 4; ++ni)
                acc[mi][ni] = __builtin_amdgcn_mfma_f32_16x16x32_bf16(
                    af[mi], bf[ni], acc[mi][ni], 0, 0, 0);
        __syncthreads();
    }

    // D layout: col = lane&15, row = quad*4 + reg
    #pragma unroll
    for (int mi = 0; mi < 4; ++mi)
        #pragma unroll
        for (int ni = 0; ni < 4; ++ni)
            #pragma unroll
            for (int r = 0; r < 4; ++r) {
                const int row = m0 + wm + mi * 16 + quad * 4 + r;
                const int col = n0 + wn + ni * 16 + l16;
                C[(size_t)row * N + col] = acc[mi][ni][r];
            }
}

// ---------------------------------------------------------------------------
// RoPE + scale + cast to f16, out of place.
// src layout (B*S, H, DH) fp32; dst same layout, f16 bits in ushort.
// ---------------------------------------------------------------------------
__global__ void rope_cast_f16(const float* __restrict__ src,
                              ushort* __restrict__ dst, int H, int total,
                              float scale) {
    int idx = blockIdx.x * blockDim.x + threadIdx.x;
    if (idx >= total) return;
    const int d   = idx & 31;
    const int h   = (idx >> 5) % H;
    const int row = idx / (32 * H);
    const int s   = row % cS;
    const float inv_freq = powf(10000.0f, -(float)d / 32.0f);
    const float ang = (float)s * inv_freq;
    const float c  = cosf(ang);
    const float si = sinf(ang);
    const float* p = src + (size_t)row * H * cDH + (size_t)h * cDH;
    const float x1 = p[d];
    const float x2 = p[d + 32];
    const float r1 = (x1 * c - x2 * si) * scale;
    const float r2 = (x2 * c + x1 * si) * scale;
    ushort* o = dst + (size_t)row * H * cDH + (size_t)h * cDH;
    o[d]      = __builtin_bit_cast(ushort, (_Float16)r1);
    o[d + 32] = __builtin_bit_cast(ushort, (_Float16)r2);
}

// ---------------------------------------------------------------------------
// Order-preserving float <-> uint bit maps (no NaNs here).
// ---------------------------------------------------------------------------
__device__ inline unsigned fmap(float f) {
    unsigned u = __float_as_uint(f);
    return (u & 0x80000000u) ? ~u : (u | 0x80000000u);
}
__device__ inline float funmap(unsigned u) {
    unsigned v = (u & 0x80000000u) ? (u & 0x7FFFFFFFu) : ~u;
    return __uint_as_float(v);
}

// ---------------------------------------------------------------------------
// Wave-per-row attention with exact top-k threshold.
// Proven constraints: key[32] 1D fully unrolled (R5/R6: 2D/runtime-indexed
// -> scratch spill, 2.4x regression); no broadcast-q MFMA (R8: 1/16 util,
// latency-bound). R10 changes vs R9:
//  - shuffle-free score layout: row = lane&15, chunk = lane>>4; butterfly
//    xor16+xor32 leaves each row's dot in the correct lane (no bpermute).
//  - pointer-increment k addressing (constant stride per u-iter).
//  - PV reads precomputed v dword-offsets from jlist.
//  - __launch_bounds__(256,4): VGPR cap 128 so the scheduler can pipeline
//    k-loads across u-iters (R9 was at 32 VGPR, 30% VALU-idle).
// Block = 256 threads = 4 waves = 4 query rows. No __syncthreads.
// ---------------------------------------------------------------------------
__global__ __launch_bounds__(256, 4) void attn_wave_kernel(
        const ushort* __restrict__ qf, const ushort* __restrict__ kf,
        const float* __restrict__ v, ushort* __restrict__ out) {
    __shared__ unsigned klist[4][cLSZ];   // keys, later overwritten by weights
    __shared__ int      jlist[4][cLSZ];   // precomputed v dword offsets

    const int lane = threadIdx.x & 63;
    const int w    = threadIdx.x >> 6;
    const int gid  = blockIdx.x * 4 + w;

    // decode: i fastest (adjacent blocks share k region -> L2 locality)
    const int i   = __builtin_amdgcn_readfirstlane(gid % cS);
    const int h   = __builtin_amdgcn_readfirstlane((gid / cS) % cQH);
    const int b   = __builtin_amdgcn_readfirstlane(gid / (cS * cQH));
    const int kvh = h / (cQH / cKVH);
    const int nb  = (i >> 6) + 1;

    const int r = lane & 15;              // k-row within 16-row group
    const int c = lane >> 4;              // 16B (8-value) chunk id 0..3

    const size_t bS = (size_t)b * cS;

    // q chunks for this lane: values [c*8, c*8+8) and [32+c*8, +8)
    const ushort* qp = qf + ((size_t)(bS + i) * cQH + h) * cDH;
    const uint4 qw0 = *(const uint4*)(qp + c * 8);
    const uint4 qw1 = *(const uint4*)(qp + 32 + c * 8);

    // per-lane k base: row r of block 0, chunk c, this (b,kvh)
    constexpr int kRowStride = cKVH * cDH;            // ushorts between j rows
    const ushort* kbase = kf + ((size_t)bS * cKVH + kvh) * cDH
                             + (size_t)r * kRowStride + c * 8;

    // --- scores -> per-lane uint keys (key[jb] is score of j = jb*64+lane) -
    unsigned key[cNB];
    #pragma unroll
    for (int jb = 0; jb < cNB; ++jb) {
        unsigned kreg = 0u;
        if (jb < nb) {
            #pragma unroll
            for (int u = 0; u < 4; ++u) {
                const ushort* kp = kbase
                    + (size_t)((jb << 6) + (u << 4)) * kRowStride;
                const uint4 kw0 = *(const uint4*)kp;
                const uint4 kw1 = *(const uint4*)(kp + 32);
                float a0 = fdot2f(kw0.x, qw0.x, 0.f);
                a0 = fdot2f(kw0.y, qw0.y, a0);
                a0 = fdot2f(kw0.z, qw0.z, a0);
                a0 = fdot2f(kw0.w, qw0.w, a0);
                float a1 = fdot2f(kw1.x, qw1.x, 0.f);
                a1 = fdot2f(kw1.y, qw1.y, a1);
                a1 = fdot2f(kw1.z, qw1.z, a1);
                a1 = fdot2f(kw1.w, qw1.w, a1);
                float acc = a0 + a1;
                // butterfly over chunk lanes {l, l^16, l^32, l^48}:
                // every lane then holds the full dot of row u*16 + (lane&15)
                acc += __shfl_xor(acc, 16);
                acc += __shfl_xor(acc, 32);
                if ((lane >> 4) == u) {
                    const int jm = (jb << 6) + lane;
                    kreg = (jm <= i) ? fmap(acc) : 0u;  // scale folded into q
                }
            }
        }
        key[jb] = kreg;
    }

    // --- row max + min over valid keys (valid keys are never 0) ------------
    unsigned um = 0u, un = 0xFFFFFFFFu;
    #pragma unroll
    for (int jb = 0; jb < cNB; ++jb) {
        if (jb >= nb) break;
        const unsigned kk = key[jb];
        um = max(um, kk);
        un = min(un, kk ? kk : 0xFFFFFFFFu);
    }
    #pragma unroll
    for (int off = 32; off >= 1; off >>= 1) {
        um = max(um, (unsigned)__shfl_xor((int)um, off));
        un = min(un, (unsigned)__shfl_xor((int)un, off));
    }
    const float mrow = funmap(um);

    // --- exact 128th-largest key via bisection in [un, um] -----------------
    unsigned lo = un, hi = um;
    while (lo < hi) {
        const unsigned d   = hi - lo;
        const unsigned mid = lo + (d >> 1) + (d & 1u);
        int cnt2 = 0;
        #pragma unroll
        for (int jb = 0; jb < cNB; ++jb) {
            if (jb >= nb) break;
            cnt2 += __popcll(__ballot(key[jb] >= mid));
        }
        if (cnt2 >= cTOPK) lo = mid; else hi = mid - 1u;
    }
    const unsigned ustar = lo;

    // --- ballot-prefix compaction of kept (j, key) into LDS ----------------
    const unsigned long long mlt = (1ull << lane) - 1ull;
    const int vbase0 = (int)(((unsigned)bS * cKVH + kvh) * cDH);
    int base = 0;
    #pragma unroll
    for (int jb = 0; jb < cNB; ++jb) {
        if (jb >= nb) break;
        const int j = (jb << 6) + lane;
        const bool keep = (j <= i) && (key[jb] >= ustar);
        const unsigned long long mk = __ballot(keep);
        const int pos = base + __popcll(mk & mlt);
        if (keep && pos < cLSZ) {
            klist[w][pos] = key[jb];
            jlist[w][pos] = vbase0 + j * (cKVH * cDH);  // v dword offset
        }
        base += __popcll(mk);
    }
    const int cnt = min(base, cLSZ);

    // --- weights + Z --------------------------------------------------------
    float zp = 0.f;
    for (int t = lane; t < cnt; t += 64) {
        const float s  = funmap(klist[w][t]);
        const float wt = __expf(s - mrow);
        ((float*)klist[w])[t] = wt;
        zp += wt;
    }
    #pragma unroll
    for (int off = 32; off >= 1; off >>= 1) zp += __shfl_xor(zp, off);
    const float invZ = 1.0f / zp;

    // --- PV: lane = d, precomputed offsets ----------------------------------
    float acc = 0.f;
    #pragma unroll 4
    for (int t = 0; t < cnt; ++t) {
        const float wt = ((float*)klist[w])[t];
        const int   vo = jlist[w][t];
        acc += wt * v[vo + lane];
    }
    out[((size_t)(bS + i) * cQH + h) * cDH + lane] = f2bf(acc * invZ);
}

// ---------------------------------------------------------------------------
// Launch
// ---------------------------------------------------------------------------
extern "C" void kernel_launch(void* const* d_in, const int* in_sizes, int n_in,
                              void* d_out, int out_size, void* d_ws, size_t ws_size,
                              hipStream_t stream) {
    const float* x  = (const float*)d_in[0];
    const float* Wq = (const float*)d_in[1];
    const float* Wk = (const float*)d_in[2];
    const float* Wv = (const float*)d_in[3];
    const float* Wo = (const float*)d_in[4];
    float* out = (float*)d_out;

    float* ws = (float*)d_ws;
    float*  qb  = ws;                                   // 4M f32 (B,S,QH,DH)
    float*  kb  = qb + (size_t)cM * cQH * cDH;          // 1M f32
    float*  vb  = kb + (size_t)cM * cKVH * cDH;         // 1M f32
    ushort* xh  = (ushort*)(vb + (size_t)cM * cKVH * cDH);  // 4M bf16
    ushort* Wqh = xh  + (size_t)cM * cD;                // 1M bf16
    ushort* Wkh = Wqh + (size_t)cQH * cDH * cD;         // 256K bf16
    ushort* Wvh = Wkh + (size_t)cKVH * cDH * cD;        // 256K bf16
    ushort* Woh = Wvh + (size_t)cKVH * cDH * cD;        // 1M bf16
    ushort* abh = Woh + (size_t)cD * cQH * cDH;         // 4M bf16
    ushort* kff = abh + (size_t)cM * cQH * cDH;         // 1M f16 (roped k)
    ushort* qff = kff + (size_t)cM * cKVH * cDH;        // 4M f16 (roped q/8)

    dim3 blk(256);

    // casts to bf16 (GEMM inputs)
    {
        const int nx  = cM * cD;
        const int nwq = cQH * cDH * cD;
        const int nwk = cKVH * cDH * cD;
        const int nwo = cD * cQH * cDH;
        cast_f32_bf16<<<(nx / 4 + 255) / 256, blk, 0, stream>>>(x, xh, nx);
        cast_f32_bf16<<<(nwq / 4 + 255) / 256, blk, 0, stream>>>(Wq, Wqh, nwq);
        cast_f32_bf16<<<(nwk / 4 + 255) / 256, blk, 0, stream>>>(Wk, Wkh, nwk);
        cast_f32_bf16<<<(nwk / 4 + 255) / 256, blk, 0, stream>>>(Wv, Wvh, nwk);
        cast_f32_bf16<<<(nwo / 4 + 255) / 256, blk, 0, stream>>>(Wo, Woh, nwo);
    }

    // QKV projections (bf16 MFMA, fp32 out)
    gemm_bf16_bt<<<dim3((cQH * cDH) / 128, cM / 128), blk, 0, stream>>>(xh, Wqh, qb, cM, cQH * cDH, cD);
    gemm_bf16_bt<<<dim3((cKVH * cDH) / 128, cM / 128), blk, 0, stream>>>(xh, Wkh, kb, cM, cKVH * cDH, cD);
    gemm_bf16_bt<<<dim3((cKVH * cDH) / 128, cM / 128), blk, 0, stream>>>(xh, Wvh, vb, cM, cKVH * cDH, cD);

    // Fused RoPE + cast to f16 (q pre-scaled by 1/sqrt(DH))
    {
        int totq = cM * cQH * 32;
        int totk = cM * cKVH * 32;
        rope_cast_f16<<<(totq + 255) / 256, blk, 0, stream>>>(qb, qff, cQH, totq, 0.125f);
        rope_cast_f16<<<(totk + 255) / 256, blk, 0, stream>>>(kb, kff, cKVH, totk, 1.0f);
    }

    // Attention (q/k f16, v fp32 in; bf16 out)
    attn_wave_kernel<<<(cB * cQH * cS) / 4, blk, 0, stream>>>(qff, kff, vb, abh);

    // Output projection (bf16 MFMA, fp32 out)
    gemm_bf16_bt<<<dim3(cD / 128, cM / 128), blk, 0, stream>>>(abh, Woh, out, cM, cD, cD);
}

// Round 11
// 837.071 us; speedup vs baseline: 1.5874x; 1.5874x over previous
//
#include <hip/hip_runtime.h>
#include <hip/hip_bf16.h>
#include <hip/hip_fp16.h>
#include <math.h>

// Problem constants
constexpr int cB   = 2;
constexpr int cS   = 2048;
constexpr int cD   = 1024;
constexpr int cQH  = 16;
constexpr int cKVH = 4;
constexpr int cDH  = 64;
constexpr int cTOPK = 128;
constexpr int cM   = cB * cS;          // 4096 rows for all GEMMs
constexpr int cNB  = cS / 64;          // 32 j-blocks of 64
constexpr int cLSZ = 384;              // kept-list capacity (128 + tie slack)

typedef __attribute__((ext_vector_type(8))) short short8;
typedef __attribute__((ext_vector_type(4))) float floatx4;
typedef _Float16 half2_t __attribute__((ext_vector_type(2)));

#if defined(__has_builtin)
#if __has_builtin(__builtin_amdgcn_fdot2)
#define HAS_FDOT2 1
#endif
#endif

// fp32 -> bf16 round-to-nearest-even (no NaN inputs in this problem)
__device__ inline ushort f2bf(float f) {
    unsigned u = __float_as_uint(f);
    return (ushort)((u + 0x7FFFu + ((u >> 16) & 1u)) >> 16);
}

// f16 pair dot with fp32 accumulate: v_dot2_f32_f16 (1 inst per 2 values)
__device__ inline float fdot2f(unsigned k, unsigned q, float c) {
#ifdef HAS_FDOT2
    return __builtin_amdgcn_fdot2(__builtin_bit_cast(half2_t, k),
                                  __builtin_bit_cast(half2_t, q), c, false);
#else
    __half2 kk = __builtin_bit_cast(__half2, k);
    __half2 qq = __builtin_bit_cast(__half2, q);
    float2 kf2 = __half22float2(kk), qf2 = __half22float2(qq);
    return c + kf2.x * qf2.x + kf2.y * qf2.y;
#endif
}

// ---------------------------------------------------------------------------
// Cast fp32 -> bf16 (raw ushort), n multiple of 4.
// ---------------------------------------------------------------------------
__global__ void cast_f32_bf16(const float* __restrict__ src,
                              ushort* __restrict__ dst, int n) {
    int i4 = (blockIdx.x * blockDim.x + threadIdx.x) * 4;
    if (i4 >= n) return;
    const float4 v = *(const float4*)(src + i4);
    ushort4 r;
    r.x = f2bf(v.x); r.y = f2bf(v.y); r.z = f2bf(v.z); r.w = f2bf(v.w);
    *(ushort4*)(dst + i4) = r;
}

// ---------------------------------------------------------------------------
// Cast fp32 -> f16 (raw ushort), n multiple of 4.
// ---------------------------------------------------------------------------
__global__ void cast_f32_f16(const float* __restrict__ src,
                             ushort* __restrict__ dst, int n) {
    int i4 = (blockIdx.x * blockDim.x + threadIdx.x) * 4;
    if (i4 >= n) return;
    const float4 v = *(const float4*)(src + i4);
    ushort4 r;
    r.x = __builtin_bit_cast(ushort, (_Float16)v.x);
    r.y = __builtin_bit_cast(ushort, (_Float16)v.y);
    r.z = __builtin_bit_cast(ushort, (_Float16)v.z);
    r.w = __builtin_bit_cast(ushort, (_Float16)v.w);
    *(ushort4*)(dst + i4) = r;
}

// ---------------------------------------------------------------------------
// MFMA bf16 GEMM: C[m][n] = sum_k A[m][k] * W[n][k]  (A @ W^T).
// 128x128 block tile, BK=32, 256 threads = 4 waves (2x2 of 64x64).
// ---------------------------------------------------------------------------
__global__ __launch_bounds__(256) void gemm_bf16_bt(
        const ushort* __restrict__ A, const ushort* __restrict__ W,
        float* __restrict__ C, int M, int N, int K) {
    __shared__ short As[4][128][8];
    __shared__ short Bs[4][128][8];

    const int tid  = threadIdx.x;
    const int lane = tid & 63;
    const int w    = tid >> 6;          // 0..3
    const int wm   = (w & 1) * 64;
    const int wn   = (w >> 1) * 64;
    const int m0   = blockIdx.y * 128;
    const int n0   = blockIdx.x * 128;

    const int quad = lane >> 4;
    const int l16  = lane & 15;

    floatx4 acc[4][4];
    #pragma unroll
    for (int mi = 0; mi < 4; ++mi)
        #pragma unroll
        for (int ni = 0; ni < 4; ++ni)
            acc[mi][ni] = (floatx4){0.f, 0.f, 0.f, 0.f};

    const int sr = tid >> 1;            // staging row 0..127
    const int sh = (tid & 1) * 2;       // k-chunk pair 0 or 2

    for (int k0 = 0; k0 < K; k0 += 32) {
        const ushort* sa = A + (size_t)(m0 + sr) * K + k0 + sh * 8;
        const short8 a0 = *(const short8*)sa;
        const short8 a1 = *(const short8*)(sa + 8);
        const ushort* sw = W + (size_t)(n0 + sr) * K + k0 + sh * 8;
        const short8 b0 = *(const short8*)sw;
        const short8 b1 = *(const short8*)(sw + 8);
        *(short8*)&As[sh][sr][0]     = a0;
        *(short8*)&As[sh + 1][sr][0] = a1;
        *(short8*)&Bs[sh][sr][0]     = b0;
        *(short8*)&Bs[sh + 1][sr][0] = b1;
        __syncthreads();

        short8 af[4], bf[4];
        #pragma unroll
        for (int mi = 0; mi < 4; ++mi)
            af[mi] = *(const short8*)&As[quad][wm + mi * 16 + l16][0];
        #pragma unroll
        for (int ni = 0; ni < 4; ++ni)
            bf[ni] = *(const short8*)&Bs[quad][wn + ni * 16 + l16][0];
        #pragma unroll
        for (int mi = 0; mi < 4; ++mi)
            #pragma unroll
            for (int ni = 0; ni < 4; ++ni)
                acc[mi][ni] = __builtin_amdgcn_mfma_f32_16x16x32_bf16(
                    af[mi], bf[ni], acc[mi][ni], 0, 0, 0);
        __syncthreads();
    }

    // D layout: col = lane&15, row = quad*4 + reg
    #pragma unroll
    for (int mi = 0; mi < 4; ++mi)
        #pragma unroll
        for (int ni = 0; ni < 4; ++ni)
            #pragma unroll
            for (int r = 0; r < 4; ++r) {
                const int row = m0 + wm + mi * 16 + quad * 4 + r;
                const int col = n0 + wn + ni * 16 + l16;
                C[(size_t)row * N + col] = acc[mi][ni][r];
            }
}

// ---------------------------------------------------------------------------
// RoPE + scale + cast to f16, out of place.
// src layout (B*S, H, DH) fp32; dst same layout, f16 bits in ushort.
// ---------------------------------------------------------------------------
__global__ void rope_cast_f16(const float* __restrict__ src,
                              ushort* __restrict__ dst, int H, int total,
                              float scale) {
    int idx = blockIdx.x * blockDim.x + threadIdx.x;
    if (idx >= total) return;
    const int d   = idx & 31;
    const int h   = (idx >> 5) % H;
    const int row = idx / (32 * H);
    const int s   = row % cS;
    const float inv_freq = powf(10000.0f, -(float)d / 32.0f);
    const float ang = (float)s * inv_freq;
    const float c  = cosf(ang);
    const float si = sinf(ang);
    const float* p = src + (size_t)row * H * cDH + (size_t)h * cDH;
    const float x1 = p[d];
    const float x2 = p[d + 32];
    const float r1 = (x1 * c - x2 * si) * scale;
    const float r2 = (x2 * c + x1 * si) * scale;
    ushort* o = dst + (size_t)row * H * cDH + (size_t)h * cDH;
    o[d]      = __builtin_bit_cast(ushort, (_Float16)r1);
    o[d + 32] = __builtin_bit_cast(ushort, (_Float16)r2);
}

// ---------------------------------------------------------------------------
// Order-preserving float <-> uint bit maps (no NaNs here).
// ---------------------------------------------------------------------------
__device__ inline unsigned fmap(float f) {
    unsigned u = __float_as_uint(f);
    return (u & 0x80000000u) ? ~u : (u | 0x80000000u);
}
__device__ inline float funmap(unsigned u) {
    unsigned v = (u & 0x80000000u) ? (u & 0x7FFFFFFFu) : ~u;
    return __uint_as_float(v);
}

// ---------------------------------------------------------------------------
// Wave-per-row attention with exact top-k threshold.
// Proven constraints:
//  - key[32] 1D fully unrolled (R5/R6: 2D/runtime-indexed -> scratch spill).
//  - no broadcast-q MFMA (R8: 1/16 util, latency-bound).
//  - no cross-half (>=32) shuffles on the critical chain (R10: 1.7x slower).
// R11 vs R9: the dynamic-index __shfl broadcast is REMOVED via permuted key
// ownership — selection (max/min/bisection/ballot counts) is permutation-
// invariant, so lane l owns row j = jb*64 + (l&3)*16 + (l>>2) directly after
// the intra-quad xor1+xor2 butterfly. PV uses f16 v + precomputed offsets.
// Block = 256 threads = 4 waves = 4 query rows. No __syncthreads.
// ---------------------------------------------------------------------------
__global__ __launch_bounds__(256) void attn_wave_kernel(
        const ushort* __restrict__ qf, const ushort* __restrict__ kf,
        const ushort* __restrict__ vf, ushort* __restrict__ out) {
    __shared__ unsigned klist[4][cLSZ];   // keys, later overwritten by weights
    __shared__ int      jlist[4][cLSZ];   // precomputed v element offsets

    const int lane = threadIdx.x & 63;
    const int w    = threadIdx.x >> 6;
    const int gid  = blockIdx.x * 4 + w;

    // decode: i fastest (adjacent blocks share k region -> L2 locality)
    const int i   = __builtin_amdgcn_readfirstlane(gid % cS);
    const int h   = __builtin_amdgcn_readfirstlane((gid / cS) % cQH);
    const int b   = __builtin_amdgcn_readfirstlane(gid / (cS * cQH));
    const int kvh = h / (cQH / cKVH);
    const int nb  = (i >> 6) + 1;

    const int g  = lane >> 2;             // j-row group within 16
    const int cq = lane & 3;              // 16B (8-value) chunk id

    // permuted key ownership: lane l holds score of row jperm within j-block
    const int jperm = ((lane & 3) << 4) + (lane >> 2);

    const size_t bS = (size_t)b * cS;

    // q chunks for this lane: values [cq*8, cq*8+8) and [32+cq*8, +8)
    const ushort* qp = qf + ((size_t)(bS + i) * cQH + h) * cDH;
    const uint4 qw0 = *(const uint4*)(qp + cq * 8);
    const uint4 qw1 = *(const uint4*)(qp + 32 + cq * 8);

    // --- scores -> per-lane uint keys (key[jb] = score of jb*64 + jperm) ---
    unsigned key[cNB];
    #pragma unroll
    for (int jb = 0; jb < cNB; ++jb) {
        unsigned kreg = 0u;
        if (jb < nb) {
            #pragma unroll
            for (int u = 0; u < 4; ++u) {
                const int jr = (jb << 6) + (u << 4) + g;
                const ushort* kp = kf + ((size_t)(bS + jr) * cKVH + kvh) * cDH;
                const uint4 kw0 = *(const uint4*)(kp + cq * 8);
                const uint4 kw1 = *(const uint4*)(kp + 32 + cq * 8);
                float a0 = fdot2f(kw0.x, qw0.x, 0.f);
                a0 = fdot2f(kw0.y, qw0.y, a0);
                a0 = fdot2f(kw0.z, qw0.z, a0);
                a0 = fdot2f(kw0.w, qw0.w, a0);
                float a1 = fdot2f(kw1.x, qw1.x, 0.f);
                a1 = fdot2f(kw1.y, qw1.y, a1);
                a1 = fdot2f(kw1.z, qw1.z, a1);
                a1 = fdot2f(kw1.w, qw1.w, a1);
                float acc = a0 + a1;
                // intra-quad butterfly: lanes 4g..4g+3 all hold row u*16+g dot
                acc += __shfl_xor(acc, 1);
                acc += __shfl_xor(acc, 2);
                // lane keeps the u == (lane&3) iteration: row jperm
                if ((lane & 3) == u) {
                    const int jm = (jb << 6) + jperm;
                    kreg = (jm <= i) ? fmap(acc) : 0u;  // scale folded into q
                }
            }
        }
        key[jb] = kreg;
    }

    // --- row max + min over valid keys (valid keys are never 0) ------------
    unsigned um = 0u, un = 0xFFFFFFFFu;
    #pragma unroll
    for (int jb = 0; jb < cNB; ++jb) {
        if (jb >= nb) break;
        const unsigned kk = key[jb];
        um = max(um, kk);
        un = min(un, kk ? kk : 0xFFFFFFFFu);
    }
    #pragma unroll
    for (int off = 32; off >= 1; off >>= 1) {
        um = max(um, (unsigned)__shfl_xor((int)um, off));
        un = min(un, (unsigned)__shfl_xor((int)un, off));
    }
    const float mrow = funmap(um);

    // --- exact 128th-largest key via bisection in [un, um] -----------------
    unsigned lo = un, hi = um;
    while (lo < hi) {
        const unsigned d   = hi - lo;
        const unsigned mid = lo + (d >> 1) + (d & 1u);
        int cnt2 = 0;
        #pragma unroll
        for (int jb = 0; jb < cNB; ++jb) {
            if (jb >= nb) break;
            cnt2 += __popcll(__ballot(key[jb] >= mid));
        }
        if (cnt2 >= cTOPK) lo = mid; else hi = mid - 1u;
    }
    const unsigned ustar = lo;

    // --- ballot-prefix compaction of kept (j, key) into LDS ----------------
    const unsigned long long mlt = (1ull << lane) - 1ull;
    const int vbase0 = (int)(((unsigned)bS * cKVH + kvh) * cDH);
    int base = 0;
    #pragma unroll
    for (int jb = 0; jb < cNB; ++jb) {
        if (jb >= nb) break;
        const int j = (jb << 6) + jperm;
        const bool keep = (j <= i) && (key[jb] >= ustar);
        const unsigned long long mk = __ballot(keep);
        const int pos = base + __popcll(mk & mlt);
        if (keep && pos < cLSZ) {
            klist[w][pos] = key[jb];
            jlist[w][pos] = vbase0 + j * (cKVH * cDH);  // v element offset
        }
        base += __popcll(mk);
    }
    const int cnt = min(base, cLSZ);

    // --- weights + Z --------------------------------------------------------
    float zp = 0.f;
    for (int t = lane; t < cnt; t += 64) {
        const float s  = funmap(klist[w][t]);
        const float wt = __expf(s - mrow);
        ((float*)klist[w])[t] = wt;
        zp += wt;
    }
    #pragma unroll
    for (int off = 32; off >= 1; off >>= 1) zp += __shfl_xor(zp, off);
    const float invZ = 1.0f / zp;

    // --- PV: lane = d, f16 v, precomputed offsets ---------------------------
    float acc = 0.f;
    #pragma unroll 4
    for (int t = 0; t < cnt; ++t) {
        const float wt = ((float*)klist[w])[t];
        const int   vo = jlist[w][t];
        const _Float16 vv = __builtin_bit_cast(_Float16, vf[vo + lane]);
        acc += wt * (float)vv;
    }
    out[((size_t)(bS + i) * cQH + h) * cDH + lane] = f2bf(acc * invZ);
}

// ---------------------------------------------------------------------------
// Launch
// ---------------------------------------------------------------------------
extern "C" void kernel_launch(void* const* d_in, const int* in_sizes, int n_in,
                              void* d_out, int out_size, void* d_ws, size_t ws_size,
                              hipStream_t stream) {
    const float* x  = (const float*)d_in[0];
    const float* Wq = (const float*)d_in[1];
    const float* Wk = (const float*)d_in[2];
    const float* Wv = (const float*)d_in[3];
    const float* Wo = (const float*)d_in[4];
    float* out = (float*)d_out;

    float* ws = (float*)d_ws;
    float*  qb  = ws;                                   // 4M f32 (B,S,QH,DH)
    float*  kb  = qb + (size_t)cM * cQH * cDH;          // 1M f32
    float*  vb  = kb + (size_t)cM * cKVH * cDH;         // 1M f32
    ushort* xh  = (ushort*)(vb + (size_t)cM * cKVH * cDH);  // 4M bf16
    ushort* Wqh = xh  + (size_t)cM * cD;                // 1M bf16
    ushort* Wkh = Wqh + (size_t)cQH * cDH * cD;         // 256K bf16
    ushort* Wvh = Wkh + (size_t)cKVH * cDH * cD;        // 256K bf16
    ushort* Woh = Wvh + (size_t)cKVH * cDH * cD;        // 1M bf16
    ushort* abh = Woh + (size_t)cD * cQH * cDH;         // 4M bf16
    ushort* kff = abh + (size_t)cM * cQH * cDH;         // 1M f16 (roped k)
    ushort* qff = kff + (size_t)cM * cKVH * cDH;        // 4M f16 (roped q/8)
    // f16 v aliased into kb's fp32 slot (kb is dead after its rope_cast)
    ushort* vff = (ushort*)kb;                          // 1M f16

    dim3 blk(256);

    // casts to bf16 (GEMM inputs)
    {
        const int nx  = cM * cD;
        const int nwq = cQH * cDH * cD;
        const int nwk = cKVH * cDH * cD;
        const int nwo = cD * cQH * cDH;
        cast_f32_bf16<<<(nx / 4 + 255) / 256, blk, 0, stream>>>(x, xh, nx);
        cast_f32_bf16<<<(nwq / 4 + 255) / 256, blk, 0, stream>>>(Wq, Wqh, nwq);
        cast_f32_bf16<<<(nwk / 4 + 255) / 256, blk, 0, stream>>>(Wk, Wkh, nwk);
        cast_f32_bf16<<<(nwk / 4 + 255) / 256, blk, 0, stream>>>(Wv, Wvh, nwk);
        cast_f32_bf16<<<(nwo / 4 + 255) / 256, blk, 0, stream>>>(Wo, Woh, nwo);
    }

    // QKV projections (bf16 MFMA, fp32 out)
    gemm_bf16_bt<<<dim3((cQH * cDH) / 128, cM / 128), blk, 0, stream>>>(xh, Wqh, qb, cM, cQH * cDH, cD);
    gemm_bf16_bt<<<dim3((cKVH * cDH) / 128, cM / 128), blk, 0, stream>>>(xh, Wkh, kb, cM, cKVH * cDH, cD);
    gemm_bf16_bt<<<dim3((cKVH * cDH) / 128, cM / 128), blk, 0, stream>>>(xh, Wvh, vb, cM, cKVH * cDH, cD);

    // Fused RoPE + cast to f16 (q pre-scaled by 1/sqrt(DH)); v cast to f16.
    // NOTE: v cast runs after k's rope_cast so reusing kb's space is safe
    // (same stream => ordered).
    {
        int totq = cM * cQH * 32;
        int totk = cM * cKVH * 32;
        rope_cast_f16<<<(totq + 255) / 256, blk, 0, stream>>>(qb, qff, cQH, totq, 0.125f);
        rope_cast_f16<<<(totk + 255) / 256, blk, 0, stream>>>(kb, kff, cKVH, totk, 1.0f);
        const int nv = cM * cKVH * cDH;
        cast_f32_f16<<<(nv / 4 + 255) / 256, blk, 0, stream>>>(vb, vff, nv);
    }

    // Attention (q/k/v f16 in; bf16 out)
    attn_wave_kernel<<<(cB * cQH * cS) / 4, blk, 0, stream>>>(qff, kff, vff, abh);

    // Output projection (bf16 MFMA, fp32 out)
    gemm_bf16_bt<<<dim3(cD / 128, cM / 128), blk, 0, stream>>>(abh, Woh, out, cM, cD, cD);
}

// Round 12
// 823.871 us; speedup vs baseline: 1.6128x; 1.0160x over previous
//
#include <hip/hip_runtime.h>
#include <hip/hip_bf16.h>
#include <hip/hip_fp16.h>
#include <math.h>

// Problem constants
constexpr int cB   = 2;
constexpr int cS   = 2048;
constexpr int cD   = 1024;
constexpr int cQH  = 16;
constexpr int cKVH = 4;
constexpr int cDH  = 64;
constexpr int cTOPK = 128;
constexpr int cM   = cB * cS;          // 4096 rows for all GEMMs
constexpr int cNB  = cS / 64;          // 32 j-blocks of 64
constexpr int cLSZ = 384;              // kept-list capacity (128 + tie slack)

typedef __attribute__((ext_vector_type(8))) short short8;
typedef __attribute__((ext_vector_type(4))) float floatx4;
typedef _Float16 half2_t __attribute__((ext_vector_type(2)));

#if defined(__has_builtin)
#if __has_builtin(__builtin_amdgcn_fdot2)
#define HAS_FDOT2 1
#endif
#endif

// fp32 -> bf16 round-to-nearest-even (no NaN inputs in this problem)
__device__ inline ushort f2bf(float f) {
    unsigned u = __float_as_uint(f);
    return (ushort)((u + 0x7FFFu + ((u >> 16) & 1u)) >> 16);
}

// f16 pair dot with fp32 accumulate: v_dot2_f32_f16 (1 inst per 2 values)
__device__ inline float fdot2f(unsigned k, unsigned q, float c) {
#ifdef HAS_FDOT2
    return __builtin_amdgcn_fdot2(__builtin_bit_cast(half2_t, k),
                                  __builtin_bit_cast(half2_t, q), c, false);
#else
    __half2 kk = __builtin_bit_cast(__half2, k);
    __half2 qq = __builtin_bit_cast(__half2, q);
    float2 kf2 = __half22float2(kk), qf2 = __half22float2(qq);
    return c + kf2.x * qf2.x + kf2.y * qf2.y;
#endif
}

// ---------------------------------------------------------------------------
// Cast fp32 -> bf16 (raw ushort), n multiple of 4.
// ---------------------------------------------------------------------------
__global__ void cast_f32_bf16(const float* __restrict__ src,
                              ushort* __restrict__ dst, int n) {
    int i4 = (blockIdx.x * blockDim.x + threadIdx.x) * 4;
    if (i4 >= n) return;
    const float4 v = *(const float4*)(src + i4);
    ushort4 r;
    r.x = f2bf(v.x); r.y = f2bf(v.y); r.z = f2bf(v.z); r.w = f2bf(v.w);
    *(ushort4*)(dst + i4) = r;
}

// ---------------------------------------------------------------------------
// Cast fp32 -> f16 (raw ushort), n multiple of 4.
// ---------------------------------------------------------------------------
__global__ void cast_f32_f16(const float* __restrict__ src,
                             ushort* __restrict__ dst, int n) {
    int i4 = (blockIdx.x * blockDim.x + threadIdx.x) * 4;
    if (i4 >= n) return;
    const float4 v = *(const float4*)(src + i4);
    ushort4 r;
    r.x = __builtin_bit_cast(ushort, (_Float16)v.x);
    r.y = __builtin_bit_cast(ushort, (_Float16)v.y);
    r.z = __builtin_bit_cast(ushort, (_Float16)v.z);
    r.w = __builtin_bit_cast(ushort, (_Float16)v.w);
    *(ushort4*)(dst + i4) = r;
}

// ---------------------------------------------------------------------------
// MFMA bf16 GEMM: C[m][n] = sum_k A[m][k] * W[n][k]  (A @ W^T).
// 128x128 block tile, BK=32, 256 threads = 4 waves (2x2 of 64x64).
// ---------------------------------------------------------------------------
__global__ __launch_bounds__(256) void gemm_bf16_bt(
        const ushort* __restrict__ A, const ushort* __restrict__ W,
        float* __restrict__ C, int M, int N, int K) {
    __shared__ short As[4][128][8];
    __shared__ short Bs[4][128][8];

    const int tid  = threadIdx.x;
    const int lane = tid & 63;
    const int w    = tid >> 6;          // 0..3
    const int wm   = (w & 1) * 64;
    const int wn   = (w >> 1) * 64;
    const int m0   = blockIdx.y * 128;
    const int n0   = blockIdx.x * 128;

    const int quad = lane >> 4;
    const int l16  = lane & 15;

    floatx4 acc[4][4];
    #pragma unroll
    for (int mi = 0; mi < 4; ++mi)
        #pragma unroll
        for (int ni = 0; ni < 4; ++ni)
            acc[mi][ni] = (floatx4){0.f, 0.f, 0.f, 0.f};

    const int sr = tid >> 1;            // staging row 0..127
    const int sh = (tid & 1) * 2;       // k-chunk pair 0 or 2

    for (int k0 = 0; k0 < K; k0 += 32) {
        const ushort* sa = A + (size_t)(m0 + sr) * K + k0 + sh * 8;
        const short8 a0 = *(const short8*)sa;
        const short8 a1 = *(const short8*)(sa + 8);
        const ushort* sw = W + (size_t)(n0 + sr) * K + k0 + sh * 8;
        const short8 b0 = *(const short8*)sw;
        const short8 b1 = *(const short8*)(sw + 8);
        *(short8*)&As[sh][sr][0]     = a0;
        *(short8*)&As[sh + 1][sr][0] = a1;
        *(short8*)&Bs[sh][sr][0]     = b0;
        *(short8*)&Bs[sh + 1][sr][0] = b1;
        __syncthreads();

        short8 af[4], bf[4];
        #pragma unroll
        for (int mi = 0; mi < 4; ++mi)
            af[mi] = *(const short8*)&As[quad][wm + mi * 16 + l16][0];
        #pragma unroll
        for (int ni = 0; ni < 4; ++ni)
            bf[ni] = *(const short8*)&Bs[quad][wn + ni * 16 + l16][0];
        #pragma unroll
        for (int mi = 0; mi < 4; ++mi)
            #pragma unroll
            for (int ni = 0; ni < 4; ++ni)
                acc[mi][ni] = __builtin_amdgcn_mfma_f32_16x16x32_bf16(
                    af[mi], bf[ni], acc[mi][ni], 0, 0, 0);
        __syncthreads();
    }

    // D layout: col = lane&15, row = quad*4 + reg
    #pragma unroll
    for (int mi = 0; mi < 4; ++mi)
        #pragma unroll
        for (int ni = 0; ni < 4; ++ni)
            #pragma unroll
            for (int r = 0; r < 4; ++r) {
                const int row = m0 + wm + mi * 16 + quad * 4 + r;
                const int col = n0 + wn + ni * 16 + l16;
                C[(size_t)row * N + col] = acc[mi][ni][r];
            }
}

// ---------------------------------------------------------------------------
// RoPE + scale + cast to f16, out of place.
// src layout (B*S, H, DH) fp32; dst same layout, f16 bits in ushort.
// ---------------------------------------------------------------------------
__global__ void rope_cast_f16(const float* __restrict__ src,
                              ushort* __restrict__ dst, int H, int total,
                              float scale) {
    int idx = blockIdx.x * blockDim.x + threadIdx.x;
    if (idx >= total) return;
    const int d   = idx & 31;
    const int h   = (idx >> 5) % H;
    const int row = idx / (32 * H);
    const int s   = row % cS;
    const float inv_freq = powf(10000.0f, -(float)d / 32.0f);
    const float ang = (float)s * inv_freq;
    const float c  = cosf(ang);
    const float si = sinf(ang);
    const float* p = src + (size_t)row * H * cDH + (size_t)h * cDH;
    const float x1 = p[d];
    const float x2 = p[d + 32];
    const float r1 = (x1 * c - x2 * si) * scale;
    const float r2 = (x2 * c + x1 * si) * scale;
    ushort* o = dst + (size_t)row * H * cDH + (size_t)h * cDH;
    o[d]      = __builtin_bit_cast(ushort, (_Float16)r1);
    o[d + 32] = __builtin_bit_cast(ushort, (_Float16)r2);
}

// ---------------------------------------------------------------------------
// Order-preserving float <-> uint bit maps (no NaNs here).
// ---------------------------------------------------------------------------
__device__ inline unsigned fmap(float f) {
    unsigned u = __float_as_uint(f);
    return (u & 0x80000000u) ? ~u : (u | 0x80000000u);
}
__device__ inline float funmap(unsigned u) {
    unsigned v = (u & 0x80000000u) ? (u & 0x7FFFFFFFu) : ~u;
    return __uint_as_float(v);
}

// ---------------------------------------------------------------------------
// Wave-per-row attention with exact top-k threshold.
// Proven constraints:
//  - key[32] 1D fully unrolled (R5/R6: 2D/runtime-indexed -> scratch spill).
//  - no broadcast-q MFMA (R8: 1/16 util, latency-bound).
//  - no cross-half (>=32) shuffles on the critical chain (R10: 1.7x slower).
//  - permuted key ownership (R11): selection is permutation-invariant; lane l
//    owns row j = jb*64 + (l&3)*16 + (l>>2) after intra-quad xor1+xor2.
// R12 vs R11 (both MLP fixes, structure unchanged):
//  - score loop: software-pipelined k-loads (prefetch u+1 before dots of u).
//  - PV: 4 independent accumulator chains (t strided by 4) for load overlap.
// Block = 256 threads = 4 waves = 4 query rows. No __syncthreads.
// ---------------------------------------------------------------------------
__global__ __launch_bounds__(256) void attn_wave_kernel(
        const ushort* __restrict__ qf, const ushort* __restrict__ kf,
        const ushort* __restrict__ vf, ushort* __restrict__ out) {
    __shared__ unsigned klist[4][cLSZ];   // keys, later overwritten by weights
    __shared__ int      jlist[4][cLSZ];   // precomputed v element offsets

    const int lane = threadIdx.x & 63;
    const int w    = threadIdx.x >> 6;
    const int gid  = blockIdx.x * 4 + w;

    // decode: i fastest (adjacent blocks share k region -> L2 locality)
    const int i   = __builtin_amdgcn_readfirstlane(gid % cS);
    const int h   = __builtin_amdgcn_readfirstlane((gid / cS) % cQH);
    const int b   = __builtin_amdgcn_readfirstlane(gid / (cS * cQH));
    const int kvh = h / (cQH / cKVH);
    const int nb  = (i >> 6) + 1;

    const int g  = lane >> 2;             // j-row group within 16
    const int cq = lane & 3;              // 16B (8-value) chunk id

    // permuted key ownership: lane l holds score of row jperm within j-block
    const int jperm = ((lane & 3) << 4) + (lane >> 2);

    const size_t bS = (size_t)b * cS;

    // q chunks for this lane: values [cq*8, cq*8+8) and [32+cq*8, +8)
    const ushort* qp = qf + ((size_t)(bS + i) * cQH + h) * cDH;
    const uint4 qw0 = *(const uint4*)(qp + cq * 8);
    const uint4 qw1 = *(const uint4*)(qp + 32 + cq * 8);

    // --- scores -> per-lane uint keys (key[jb] = score of jb*64 + jperm) ---
    unsigned key[cNB];
    #pragma unroll
    for (int jb = 0; jb < cNB; ++jb) {
        unsigned kreg = 0u;
        if (jb < nb) {
            // software pipeline: prefetch next u's k chunks before dots of u
            const ushort* kp0 = kf + ((size_t)(bS + (jb << 6) + g) * cKVH + kvh) * cDH;
            uint4 pw0 = *(const uint4*)(kp0 + cq * 8);
            uint4 pw1 = *(const uint4*)(kp0 + 32 + cq * 8);
            #pragma unroll
            for (int u = 0; u < 4; ++u) {
                const uint4 kw0 = pw0;
                const uint4 kw1 = pw1;
                if (u < 3) {
                    const int jr = (jb << 6) + ((u + 1) << 4) + g;
                    const ushort* kp = kf + ((size_t)(bS + jr) * cKVH + kvh) * cDH;
                    pw0 = *(const uint4*)(kp + cq * 8);
                    pw1 = *(const uint4*)(kp + 32 + cq * 8);
                }
                float a0 = fdot2f(kw0.x, qw0.x, 0.f);
                a0 = fdot2f(kw0.y, qw0.y, a0);
                a0 = fdot2f(kw0.z, qw0.z, a0);
                a0 = fdot2f(kw0.w, qw0.w, a0);
                float a1 = fdot2f(kw1.x, qw1.x, 0.f);
                a1 = fdot2f(kw1.y, qw1.y, a1);
                a1 = fdot2f(kw1.z, qw1.z, a1);
                a1 = fdot2f(kw1.w, qw1.w, a1);
                float acc = a0 + a1;
                // intra-quad butterfly: lanes 4g..4g+3 all hold row u*16+g dot
                acc += __shfl_xor(acc, 1);
                acc += __shfl_xor(acc, 2);
                // lane keeps the u == (lane&3) iteration: row jperm
                if ((lane & 3) == u) {
                    const int jm = (jb << 6) + jperm;
                    kreg = (jm <= i) ? fmap(acc) : 0u;  // scale folded into q
                }
            }
        }
        key[jb] = kreg;
    }

    // --- row max + min over valid keys (valid keys are never 0) ------------
    unsigned um = 0u, un = 0xFFFFFFFFu;
    #pragma unroll
    for (int jb = 0; jb < cNB; ++jb) {
        if (jb >= nb) break;
        const unsigned kk = key[jb];
        um = max(um, kk);
        un = min(un, kk ? kk : 0xFFFFFFFFu);
    }
    #pragma unroll
    for (int off = 32; off >= 1; off >>= 1) {
        um = max(um, (unsigned)__shfl_xor((int)um, off));
        un = min(un, (unsigned)__shfl_xor((int)un, off));
    }
    const float mrow = funmap(um);

    // --- exact 128th-largest key via bisection in [un, um] -----------------
    unsigned lo = un, hi = um;
    while (lo < hi) {
        const unsigned d   = hi - lo;
        const unsigned mid = lo + (d >> 1) + (d & 1u);
        int cnt2 = 0;
        #pragma unroll
        for (int jb = 0; jb < cNB; ++jb) {
            if (jb >= nb) break;
            cnt2 += __popcll(__ballot(key[jb] >= mid));
        }
        if (cnt2 >= cTOPK) lo = mid; else hi = mid - 1u;
    }
    const unsigned ustar = lo;

    // --- ballot-prefix compaction of kept (j, key) into LDS ----------------
    const unsigned long long mlt = (1ull << lane) - 1ull;
    const int vbase0 = (int)(((unsigned)bS * cKVH + kvh) * cDH);
    int base = 0;
    #pragma unroll
    for (int jb = 0; jb < cNB; ++jb) {
        if (jb >= nb) break;
        const int j = (jb << 6) + jperm;
        const bool keep = (j <= i) && (key[jb] >= ustar);
        const unsigned long long mk = __ballot(keep);
        const int pos = base + __popcll(mk & mlt);
        if (keep && pos < cLSZ) {
            klist[w][pos] = key[jb];
            jlist[w][pos] = vbase0 + j * (cKVH * cDH);  // v element offset
        }
        base += __popcll(mk);
    }
    const int cnt = min(base, cLSZ);

    // --- weights + Z --------------------------------------------------------
    float zp = 0.f;
    for (int t = lane; t < cnt; t += 64) {
        const float s  = funmap(klist[w][t]);
        const float wt = __expf(s - mrow);
        ((float*)klist[w])[t] = wt;
        zp += wt;
    }
    #pragma unroll
    for (int off = 32; off >= 1; off >>= 1) zp += __shfl_xor(zp, off);
    const float invZ = 1.0f / zp;

    // --- PV: lane = d, f16 v, 4 independent accumulator chains --------------
    float ac0 = 0.f, ac1 = 0.f, ac2 = 0.f, ac3 = 0.f;
    int t = 0;
    #pragma unroll 2
    for (; t + 3 < cnt; t += 4) {
        const float wt0 = ((float*)klist[w])[t];
        const float wt1 = ((float*)klist[w])[t + 1];
        const float wt2 = ((float*)klist[w])[t + 2];
        const float wt3 = ((float*)klist[w])[t + 3];
        const int vo0 = jlist[w][t];
        const int vo1 = jlist[w][t + 1];
        const int vo2 = jlist[w][t + 2];
        const int vo3 = jlist[w][t + 3];
        ac0 += wt0 * (float)__builtin_bit_cast(_Float16, vf[vo0 + lane]);
        ac1 += wt1 * (float)__builtin_bit_cast(_Float16, vf[vo1 + lane]);
        ac2 += wt2 * (float)__builtin_bit_cast(_Float16, vf[vo2 + lane]);
        ac3 += wt3 * (float)__builtin_bit_cast(_Float16, vf[vo3 + lane]);
    }
    for (; t < cnt; ++t) {
        const float wt = ((float*)klist[w])[t];
        const int   vo = jlist[w][t];
        ac0 += wt * (float)__builtin_bit_cast(_Float16, vf[vo + lane]);
    }
    const float acc = (ac0 + ac1) + (ac2 + ac3);
    out[((size_t)(bS + i) * cQH + h) * cDH + lane] = f2bf(acc * invZ);
}

// ---------------------------------------------------------------------------
// Launch
// ---------------------------------------------------------------------------
extern "C" void kernel_launch(void* const* d_in, const int* in_sizes, int n_in,
                              void* d_out, int out_size, void* d_ws, size_t ws_size,
                              hipStream_t stream) {
    const float* x  = (const float*)d_in[0];
    const float* Wq = (const float*)d_in[1];
    const float* Wk = (const float*)d_in[2];
    const float* Wv = (const float*)d_in[3];
    const float* Wo = (const float*)d_in[4];
    float* out = (float*)d_out;

    float* ws = (float*)d_ws;
    float*  qb  = ws;                                   // 4M f32 (B,S,QH,DH)
    float*  kb  = qb + (size_t)cM * cQH * cDH;          // 1M f32
    float*  vb  = kb + (size_t)cM * cKVH * cDH;         // 1M f32
    ushort* xh  = (ushort*)(vb + (size_t)cM * cKVH * cDH);  // 4M bf16
    ushort* Wqh = xh  + (size_t)cM * cD;                // 1M bf16
    ushort* Wkh = Wqh + (size_t)cQH * cDH * cD;         // 256K bf16
    ushort* Wvh = Wkh + (size_t)cKVH * cDH * cD;        // 256K bf16
    ushort* Woh = Wvh + (size_t)cKVH * cDH * cD;        // 1M bf16
    ushort* abh = Woh + (size_t)cD * cQH * cDH;         // 4M bf16
    ushort* kff = abh + (size_t)cM * cQH * cDH;         // 1M f16 (roped k)
    ushort* qff = kff + (size_t)cM * cKVH * cDH;        // 4M f16 (roped q/8)
    // f16 v aliased into kb's fp32 slot (kb is dead after its rope_cast)
    ushort* vff = (ushort*)kb;                          // 1M f16

    dim3 blk(256);

    // casts to bf16 (GEMM inputs)
    {
        const int nx  = cM * cD;
        const int nwq = cQH * cDH * cD;
        const int nwk = cKVH * cDH * cD;
        const int nwo = cD * cQH * cDH;
        cast_f32_bf16<<<(nx / 4 + 255) / 256, blk, 0, stream>>>(x, xh, nx);
        cast_f32_bf16<<<(nwq / 4 + 255) / 256, blk, 0, stream>>>(Wq, Wqh, nwq);
        cast_f32_bf16<<<(nwk / 4 + 255) / 256, blk, 0, stream>>>(Wk, Wkh, nwk);
        cast_f32_bf16<<<(nwk / 4 + 255) / 256, blk, 0, stream>>>(Wv, Wvh, nwk);
        cast_f32_bf16<<<(nwo / 4 + 255) / 256, blk, 0, stream>>>(Wo, Woh, nwo);
    }

    // QKV projections (bf16 MFMA, fp32 out)
    gemm_bf16_bt<<<dim3((cQH * cDH) / 128, cM / 128), blk, 0, stream>>>(xh, Wqh, qb, cM, cQH * cDH, cD);
    gemm_bf16_bt<<<dim3((cKVH * cDH) / 128, cM / 128), blk, 0, stream>>>(xh, Wkh, kb, cM, cKVH * cDH, cD);
    gemm_bf16_bt<<<dim3((cKVH * cDH) / 128, cM / 128), blk, 0, stream>>>(xh, Wvh, vb, cM, cKVH * cDH, cD);

    // Fused RoPE + cast to f16 (q pre-scaled by 1/sqrt(DH)); v cast to f16.
    // NOTE: v cast runs after k's rope_cast so reusing kb's space is safe
    // (same stream => ordered).
    {
        int totq = cM * cQH * 32;
        int totk = cM * cKVH * 32;
        rope_cast_f16<<<(totq + 255) / 256, blk, 0, stream>>>(qb, qff, cQH, totq, 0.125f);
        rope_cast_f16<<<(totk + 255) / 256, blk, 0, stream>>>(kb, kff, cKVH, totk, 1.0f);
        const int nv = cM * cKVH * cDH;
        cast_f32_f16<<<(nv / 4 + 255) / 256, blk, 0, stream>>>(vb, vff, nv);
    }

    // Attention (q/k/v f16 in; bf16 out)
    attn_wave_kernel<<<(cB * cQH * cS) / 4, blk, 0, stream>>>(qff, kff, vff, abh);

    // Output projection (bf16 MFMA, fp32 out)
    gemm_bf16_bt<<<dim3(cD / 128, cM / 128), blk, 0, stream>>>(abh, Woh, out, cM, cD, cD);
}